// Round 6
// baseline (10943.333 us; speedup 1.0000x reference)
//
#include <hip/hip_runtime.h>
#include <hip/hip_bf16.h>

// Problem constants
#define BATCH   64
#define SEQ     512
#define DMODEL  256
#define HIDDEN  512
#define G3      1536      // 3*HIDDEN
#define CHUNK   128       // timesteps per scan chunk-kernel
#define NCHUNK  4         // SEQ / CHUNK

// v13 batch-group decomposition
#define GROUPS  8         // independent sample groups (one per XCD, heuristically)
#define SPG     8         // samples per group (64/8)
#define BPG     16        // blocks per group
#define UPB     32        // units per block (512/16)
#define CPBK    96        // gate cols per block (3*UPB)
#define HSLOTG  (HIDDEN * SPG)          // 4096 floats per group h-slot (16 KB)
#define HGSTRIDE ((long)CHUNK * HSLOTG) // floats per group's history

typedef unsigned long long u64;
typedef unsigned int u32;

// ---------------------------------------------------------------------------
// Pack Wh slices for v13: whp[(p*96+c)*512 + k] = Wh[k][gate*512 + p*32 + u]
// where c = gate*32 + u. Each block p streams its 196 KB slice from L2 every
// step (all 8 groups share slice p -> every XCD's L2 caches the full 3 MB).
// ---------------------------------------------------------------------------
__global__ __launch_bounds__(512) void prep_wh(const float* __restrict__ Wh,
                                               float* __restrict__ whp) {
    int t = blockIdx.x * 512 + threadIdx.x;      // 0 .. 786431
    int k  = t & 511;
    int cb = t >> 9;           // p*96 + c,  0..1535
    int c  = cb % CPBK;
    int p  = cb / CPBK;
    int gate = c >> 5, u = c & 31;
    whp[t] = Wh[(long)k * G3 + gate * HIDDEN + p * UPB + u];
}

// ---------------------------------------------------------------------------
// Zero the 512 flags (8 groups x 16 blocks x 4 producer-waves) with
// agent-scope stores. Flags are monotonic global-step values across all
// 4 chunk kernels, initialized exactly once per launch.
// ---------------------------------------------------------------------------
__global__ void init_flags(unsigned* flags) {
    __hip_atomic_store(&flags[threadIdx.x], 0u, __ATOMIC_RELAXED,
                       __HIP_MEMORY_SCOPE_AGENT);
}

// ---------------------------------------------------------------------------
// Chunked xg GEMM: xgC[col][lt][b] = emb[ids[b][s]] . Wx[:,col] + bx[col],
// s = chunk*CHUNK + lt. Unchanged from v8-v12.
// ---------------------------------------------------------------------------
__global__ __launch_bounds__(256) void xg_gemm(const int* __restrict__ ids,
                                               const float* __restrict__ emb,
                                               const float* __restrict__ Wx,
                                               const float* __restrict__ bx,
                                               float* __restrict__ xgC,
                                               int chunk) {
    __shared__ float Es[64][68];   // Es[k][b], padded
    __shared__ float Ws[64][68];   // Ws[k][c], padded
    __shared__ int   sids[64];

    const int tid = threadIdx.x;
    const int nb = blockIdx.x;     // col tile 0..23
    const int lt = blockIdx.y;     // local timestep 0..127
    const int s  = chunk * CHUNK + lt;
    const int tn = tid & 15;
    const int tm = tid >> 4;

    if (tid < 64) sids[tid] = ids[tid * SEQ + s];
    __syncthreads();

    float acc[4][4];
#pragma unroll
    for (int i = 0; i < 4; ++i)
#pragma unroll
        for (int j = 0; j < 4; ++j) acc[i][j] = 0.f;

    for (int kb = 0; kb < 256; kb += 64) {
#pragma unroll
        for (int p = 0; p < 4; ++p) {
            int b = p * 16 + tm;
            float4 av = *(const float4*)(emb + (long)sids[b] * DMODEL + kb + tn * 4);
            Es[tn * 4 + 0][b] = av.x;
            Es[tn * 4 + 1][b] = av.y;
            Es[tn * 4 + 2][b] = av.z;
            Es[tn * 4 + 3][b] = av.w;
            int krow = p * 16 + tm;
            float4 wv = *(const float4*)(Wx + (long)(kb + krow) * G3 + nb * 64 + tn * 4);
            *(float4*)&Ws[krow][tn * 4] = wv;
        }
        __syncthreads();
#pragma unroll
        for (int k = 0; k < 64; ++k) {
            float4 w4 = *(const float4*)&Ws[k][tm * 4];
            float4 e4 = *(const float4*)&Es[k][tn * 4];
            float ww[4] = {w4.x, w4.y, w4.z, w4.w};
            float ee[4] = {e4.x, e4.y, e4.z, e4.w};
#pragma unroll
            for (int i = 0; i < 4; ++i)
#pragma unroll
                for (int j = 0; j < 4; ++j)
                    acc[i][j] = fmaf(ww[i], ee[j], acc[i][j]);
        }
        __syncthreads();
    }

#pragma unroll
    for (int i = 0; i < 4; ++i) {
        int col = nb * 64 + tm * 4 + i;
        float bxi = bx[col];
        float4 o;
        o.x = acc[i][0] + bxi;
        o.y = acc[i][1] + bxi;
        o.z = acc[i][2] + bxi;
        o.w = acc[i][3] + bxi;
        *(float4*)(xgC + (long)col * (CHUNK * BATCH) + lt * 64 + tn * 4) = o;
    }
}

// ---------------------------------------------------------------------------
// GRU scan v13: batch-group decomposition -- keep the h exchange on ONE XCD.
// v8-v12 ablation: five different handoff protocols all floor at 8.5-10
// us/step, and plain-vs-agent bulk reads are identical -> the floor is the
// GPU-GLOBAL all-to-all through the MALL (cross-XCD store->visible->detect->
// fetch), paced by the slowest of 128 blocks. Topology fix: the batch dim
// is embarrassingly parallel (h[t+1][b] depends only on h[t][b]), so split
// into 8 INDEPENDENT groups of 8 samples. Group = blockIdx&7: under the
// round-robin blockIdx->XCD mapping, a group's 16 blocks land on one XCD
// and the whole exchange chain runs through the local L2 (~200-400cy legs).
// Placement is a performance heuristic ONLY: the agent-scope protocol is
// placement-independent (v11/v12 proved it cross-XCD).
//  * block (g,p): samples g*8..g*8+7, units p*32..p*32+31 (96 gate cols).
//  * T=768 (12 waves). FMA role (all): lane=(c8,s); wave wv handles cols
//    wv*8..wv*8+7; weights streamed from L2 (196 KB/block/step, overlapped
//    with FMA); h[t] read from LDS hl[s][k] (padded 516: the 8 distinct
//    b128 reads per instr cover all 32 banks exactly once; 8-way same-
//    address replication is free broadcast).
//  * producer role (waves 0-3, threads (u,s)): nonlin from LDS gl + xg
//    (prefetched one step ahead), write-through h store (contiguous 128 B
//    runs), per-WAVE vmcnt(0) drain, per-wave flag (4 flags/block) -- the
//    producer tail is wave-local, no extra barrier.
//  * consumer role (waves 4-11): poll the group's 64 flags (one coalesced
//    agent load/iter), then stage the 16 KB h slot into LDS (j=tid-256:
//    float8 per thread, contiguous).
//  * 2 barriers/step: gl-ready, hl-ready.
// Correctness:
//  * flag >= t implies the producing wave's h rows are at the coherence
//    point (own-store drain precedes flag store); flags monotonic.
//  * skew <= 1 step within a group << 128-slot reuse distance; groups are
//    mutually independent (no cross-group reads at all).
//  * chunk carry: slot 0 written by prev chunk's last step; entry staging
//    (chunk>0) reads it after kernel-entry acquire; chunk 0 skips step 0
//    analytically (h0=0).
// Deadlock-free: 128 blocks co-resident (<=256 CUs, 12 waves/block, ~20 KB
// LDS); within a block every thread reaches both barriers every iteration;
// within a group forward progress by induction on t.
// ---------------------------------------------------------------------------
__global__ __launch_bounds__(768, 1) void gru_scan(const float* __restrict__ whp,
                                                   const float* __restrict__ xgC,
                                                   const float* __restrict__ bh,
                                                   float* hist,
                                                   unsigned* flags,
                                                   int chunk) {
    const int tid = threadIdx.x;
    const int g   = blockIdx.x & 7;                            // group (XCD-affine)
    const int p   = blockIdx.x >> 3;                           // unit tile 0..15
    const int wv  = __builtin_amdgcn_readfirstlane(tid >> 6);  // wave 0..11
    const int ln  = tid & 63;

    __shared__ float hl[SPG][516];    // h[t] as [sample][k], pad 4 -> conflict-free
    __shared__ float gl[CPBK][9];     // gate dot-products [c][s], pad -> conflict-free

    float* hist_g = hist + (long)g * HGSTRIDE;
    unsigned* flg = flags + g * 64;
    const int base = chunk * CHUNK;

    // FMA-role constants (all 768 threads)
    const int c8 = ln >> 3;           // col-within-wave 0..7
    const int sf = ln & 7;            // sample 0..7
    const int cl = wv * 8 + c8;       // local col 0..95
    const float* wp = whp + (long)(p * CPBK + cl) * HIDDEN;

    // producer-role state (waves 0-3: thread = (u = tid&31, sp = tid>>5))
    int u = 0, sp = 0, ju = 0;
    float bhr = 0.f, bhz = 0.f, bhn = 0.f, hprev = 0.f;
    float xr = 0.f, xz = 0.f, xn = 0.f;
    const float* xr_p = nullptr; const float* xz_p = nullptr; const float* xn_p = nullptr;
    if (wv < 4) {
        u  = tid & 31;
        sp = tid >> 5;
        ju = p * UPB + u;                      // global unit
        bhr = bh[ju];
        bhz = bh[HIDDEN + ju];
        bhn = bh[2 * HIDDEN + ju];
        const int b = g * SPG + sp;            // global sample
        xr_p = xgC + (long)ju * (CHUNK * BATCH) + b;
        xz_p = xgC + (long)(HIDDEN + ju) * (CHUNK * BATCH) + b;
        xn_p = xgC + (long)(2 * HIDDEN + ju) * (CHUNK * BATCH) + b;
        // cross-chunk carry: slot 0 (fresh via kernel-entry acquire)
        hprev = (chunk == 0) ? 0.f : hist_g[(long)sp * HIDDEN + ju];
        // prefetch xg for lt=0
        xr = xr_p[0]; xz = xz_p[0]; xn = xn_p[0];
    } else if (chunk > 0) {
        // stage h[base] (slot 0) for the first iteration
        const int j  = tid - 256;              // 0..511
        const int ss = j >> 6;                 // sample
        const int u8 = (j & 63) << 3;          // unit octet
        const float* src = hist_g + (long)ss * HIDDEN + u8;
        *(float4*)&hl[ss][u8]     = *(const float4*)(src);
        *(float4*)&hl[ss][u8 + 4] = *(const float4*)(src + 4);
    }
    __syncthreads();                           // hl[base] ready

#pragma unroll 1
    for (int lt = 0; lt < CHUNK; ++lt) {
        const int t = base + lt;

        // ---- FMA phase: acc = sum_k h[t][sf][k] * Wh[k][col] ----
        float acc = 0.f;
        if (t > 0) {
#pragma unroll 4
            for (int k = 0; k < HIDDEN; k += 8) {
                float4 w0 = *(const float4*)(wp + k);
                float4 w1 = *(const float4*)(wp + k + 4);
                float4 h0 = *(const float4*)&hl[sf][k];
                float4 h1 = *(const float4*)&hl[sf][k + 4];
                acc = fmaf(h0.x, w0.x, acc);
                acc = fmaf(h0.y, w0.y, acc);
                acc = fmaf(h0.z, w0.z, acc);
                acc = fmaf(h0.w, w0.w, acc);
                acc = fmaf(h1.x, w1.x, acc);
                acc = fmaf(h1.y, w1.y, acc);
                acc = fmaf(h1.z, w1.z, acc);
                acc = fmaf(h1.w, w1.w, acc);
            }
        }
        gl[cl][sf] = acc;
        __syncthreads();                       // gl ready

        if (wv < 4) {
            // ---- producer tail: nonlin -> store -> own-drain -> flag ----
            float hgr = gl[u][sp] + bhr;
            float hgz = gl[32 + u][sp] + bhz;
            float hgn = gl[64 + u][sp] + bhn;
            float r  = 1.f / (1.f + expf(-(xr + hgr)));
            float z  = 1.f / (1.f + expf(-(xz + hgz)));
            float nn = tanhf(xn + r * hgn);
            float hnew = (1.f - z) * nn + z * hprev;
            hprev = hnew;
            float* hw = hist_g + (long)((lt + 1) & (CHUNK - 1)) * HSLOTG
                        + (long)sp * HIDDEN + ju;
            __hip_atomic_store((u32*)hw, __float_as_uint(hnew),
                               __ATOMIC_RELAXED, __HIP_MEMORY_SCOPE_AGENT);
            asm volatile("s_waitcnt vmcnt(0)" ::: "memory");   // own stores at L2/MALL
            if (ln == 0)
                __hip_atomic_store(&flg[p * 4 + wv], (u32)(t + 1),
                                   __ATOMIC_RELAXED, __HIP_MEMORY_SCOPE_AGENT);
            // prefetch xg for the next step (after drain: not on the drain path)
            if (lt + 1 < CHUNK) {
                xr = xr_p[(lt + 1) * 64];
                xz = xz_p[(lt + 1) * 64];
                xn = xn_p[(lt + 1) * 64];
            }
        } else if (lt + 1 < CHUNK) {
            // ---- consumer: poll the group's 64 flags, stage h[t+1] ----
            const u32 tgt = (u32)(t + 1);
            for (;;) {
                u32 f = __hip_atomic_load(&flg[ln], __ATOMIC_RELAXED,
                                          __HIP_MEMORY_SCOPE_AGENT);
                if (__all((int)(f >= tgt))) break;
                __builtin_amdgcn_s_sleep(1);
            }
            asm volatile("" ::: "memory");     // no hoist of the staging loads
            const int j  = tid - 256;
            const int ss = j >> 6;
            const int u8 = (j & 63) << 3;
            const float* src = hist_g + (long)((lt + 1) & (CHUNK - 1)) * HSLOTG
                               + (long)ss * HIDDEN + u8;
            *(float4*)&hl[ss][u8]     = *(const float4*)(src);
            *(float4*)&hl[ss][u8 + 4] = *(const float4*)(src + 4);
        }
        __syncthreads();                       // hl[t+1] ready
    }
}

// ---------------------------------------------------------------------------
// head: logits[b][n] = sum_k h[k][b] * Wo[k][n] + bo[n]
// h[512] sits in each group's slot 0: hist[g][0][s][k] layout.
// ---------------------------------------------------------------------------
__global__ void head_kernel(const float* __restrict__ hist,
                            const float* __restrict__ Wo,
                            const float* __restrict__ bo,
                            float* __restrict__ out) {
    int tid = threadIdx.x;        // 128 threads
    int b = tid >> 1, n = tid & 1;
    const float* hrow = hist + (long)(b >> 3) * HGSTRIDE + (long)(b & 7) * HIDDEN;
    float acc = bo[n];
#pragma unroll 8
    for (int k = 0; k < HIDDEN; ++k)
        acc = fmaf(hrow[k], Wo[k * 2 + n], acc);
    out[b * 2 + n] = acc;
}

// ---------------------------------------------------------------------------
extern "C" void kernel_launch(void* const* d_in, const int* in_sizes, int n_in,
                              void* d_out, int out_size, void* d_ws, size_t ws_size,
                              hipStream_t stream) {
    (void)in_sizes; (void)n_in; (void)out_size; (void)ws_size;
    const int*   ids = (const int*)  d_in[0];
    const float* emb = (const float*)d_in[1];
    const float* Wx  = (const float*)d_in[2];
    const float* Wh  = (const float*)d_in[3];
    const float* bx  = (const float*)d_in[4];
    const float* bh  = (const float*)d_in[5];
    const float* Wo  = (const float*)d_in[6];
    const float* bo  = (const float*)d_in[7];
    float* out = (float*)d_out;

    char* ws = (char*)d_ws;
    // ws layout: [flags 2KB][hist 16MB][whp 3MB][xgC 50.3MB]  (~70 MB total)
    // hist: 8 groups x 128 slots x (8 samples x 512 units). No init needed:
    // every slot is written before it is read (chunk0/lt0 is analytic).
    unsigned* flags = (unsigned*)ws;
    float* hist = (float*)(ws + 2048);
    float* whp  = (float*)(ws + 2048 + (size_t)GROUPS * HGSTRIDE * 4);
    float* xgC  = (float*)(ws + 2048 + (size_t)GROUPS * HGSTRIDE * 4
                           + (size_t)BPG * CPBK * HIDDEN * 4);

    init_flags<<<dim3(1), dim3(512), 0, stream>>>(flags);
    prep_wh<<<dim3(1536), dim3(512), 0, stream>>>(Wh, whp);
    for (int c = 0; c < NCHUNK; ++c) {
        xg_gemm<<<dim3(24, CHUNK), dim3(256), 0, stream>>>(ids, emb, Wx, bx, xgC, c);
        gru_scan<<<dim3(GROUPS * BPG), dim3(768), 0, stream>>>(whp, xgC, bh, hist, flags, c);
    }
    head_kernel<<<dim3(1), dim3(128), 0, stream>>>(hist, Wo, bo, out);
}